// Round 5
// baseline (1471.296 us; speedup 1.0000x reference)
//
#include <hip/hip_runtime.h>

// SimpleLSTM: 2-layer LSTM (B=512,T=256,F=64,U=128) + Dense(1,relu).
// R13: cross-CU layer overlap with a REGULAR launch (R12 used cooperative
// launch, which appears incompatible with the harness's graph capture ->
// output stayed zero). Dependency is one-way (A publishes prog, B waits,
// A never waits), so a plain 512-WG launch cannot deadlock under ANY
// dispatch order: co-resident -> overlap; not co-resident -> B runs after
// A completes (correct, ~R8 speed). WG bid<256 = layer A pair bid; bid>=256
// = layer B pair bid-256, reading hs from global gated by a device-scope
// produced-block counter (A publishes 1x/8 steps; B needs block k+2 before
// stepping block k => self-enforcing 16-step skew). bid and bid+256 share
// an XCD (256%8==0) -> hs handoff is XCD-local L2. Each CU hosts one A-WG
// + one B-WG with unsynchronized barriers -> one WG's MFMAs fill the
// other's stalls. Target ~272 x step-time instead of 512 x.

#define T_STEPS 256
#define BATCH   512
#define NU      128
#define FDIM    64

typedef _Float16 h8 __attribute__((ext_vector_type(8)));
typedef _Float16 h4 __attribute__((ext_vector_type(4)));
typedef float    f4 __attribute__((ext_vector_type(4)));

#define LOG2E    1.4426950408889634f
#define TWOLOG2E 2.8853900817779268f

// Workgroup barrier draining LDS only (no vmcnt drain; all cross-step deps
// are LDS, global loads wait at use, stores have no in-kernel reader).
#define WG_BARRIER() asm volatile("s_waitcnt lgkmcnt(0)\n\ts_barrier" ::: "memory")

#if __has_builtin(__builtin_amdgcn_exp2f)
#define EXP2F(x) __builtin_amdgcn_exp2f(x)
#else
#define EXP2F(x) exp2f(x)
#endif
#if __has_builtin(__builtin_amdgcn_rcpf)
#define RCPF(x) __builtin_amdgcn_rcpf(x)
#else
#define RCPF(x) (1.0f / (x))
#endif

// s = -z*log2e (sign folded into weights) -> sigmoid(z)
__device__ __forceinline__ float sigm2(float s) {
    return RCPF(1.0f + EXP2F(s));
}
// t = 2*z*log2e -> tanh(z)
__device__ __forceinline__ float tanh2(float t) {
    return 1.0f - 2.0f * RCPF(1.0f + EXP2F(t));
}

// ---- weight prep: col-major [col][k], fp16, fold gate-specific log2e ----
// gates: 0=i 1=f 2=g 3=o ; i/f/o scaled by -log2e (sigm2), g by +2log2e.
// Also zeroes the 512-entry progress-counter array (re-run safe).
__global__ void prep_weights(const float* __restrict__ W1, const float* __restrict__ U1,
                             const float* __restrict__ b1, const float* __restrict__ W2,
                             const float* __restrict__ U2, const float* __restrict__ b2,
                             _Float16* __restrict__ Wp1, _Float16* __restrict__ Up1,
                             _Float16* __restrict__ Wp2, _Float16* __restrict__ Up2,
                             float* __restrict__ bp1, float* __restrict__ bp2,
                             int* __restrict__ prog) {
    int i = blockIdx.x * 256 + threadIdx.x;
    if (i < 32768) {                       // Wp1 [512][64] from W1 [64][512]
        int col = i >> 6, k = i & 63;
        float sc = ((col >> 7) == 2) ? TWOLOG2E : -LOG2E;
        Wp1[i] = (_Float16)(W1[k * 512 + col] * sc);
    } else if (i < 32768 + 65536) {        // Up1 [512][128] from U1 [128][512]
        int j = i - 32768; int col = j >> 7, k = j & 127;
        float sc = ((col >> 7) == 2) ? TWOLOG2E : -LOG2E;
        Up1[j] = (_Float16)(U1[k * 512 + col] * sc);
    } else if (i < 32768 + 131072) {       // Wp2 [512][128] from W2 [128][512]
        int j = i - 98304; int col = j >> 7, k = j & 127;
        float sc = ((col >> 7) == 2) ? TWOLOG2E : -LOG2E;
        Wp2[j] = (_Float16)(W2[k * 512 + col] * sc);
    } else if (i < 32768 + 196608) {       // Up2 [512][128] from U2 [128][512]
        int j = i - 163840; int col = j >> 7, k = j & 127;
        float sc = ((col >> 7) == 2) ? TWOLOG2E : -LOG2E;
        Up2[j] = (_Float16)(U2[k * 512 + col] * sc);
    } else if (i < 32768 + 196608 + 1024) {
        int j = i - 229376;
        if (j < 512) {
            float sc = ((j >> 7) == 2) ? TWOLOG2E : -LOG2E;
            bp1[j] = b1[j] * sc;
        } else {
            int col = j - 512;
            float sc = ((col >> 7) == 2) ? TWOLOG2E : -LOG2E;
            bp2[col] = b2[col] * sc;
        }
    } else if (i < 230912) {               // prog[512] = 0
        prog[i - 230400] = 0;
    }
}

#define PH 136            // h ring row stride in halfs (272 B, 16B-aligned)

// ---- one LSTM layer body (R8 structure) ----
// IS_A: input = x (f32 [B,T,F]), writes hs fp16 [T,B,U], publishes prog.
// !IS_A: input = hs (fp16 [T,B,U]) gated on prog, fused dense at end.
template <bool IS_A>
__device__ __forceinline__ void layer_body(
    const int pair,
    const float* __restrict__ xA, const _Float16* __restrict__ xB,
    const _Float16* __restrict__ Wp,   // [512][KX] col-major, scaled fp16
    const _Float16* __restrict__ Up,   // [512][128] col-major, scaled fp16
    const float* __restrict__ bp,      // [512] scaled
    _Float16* __restrict__ hs_out,
    const float* __restrict__ Wd, const float* __restrict__ bd,
    float* __restrict__ dout,
    int* __restrict__ prog,
    _Float16* smh, float* smxz) {
    constexpr int KX  = IS_A ? 64 : 128;
    constexpr int KXS = KX / 32;
    const int H0 = 0;                  // h buffers: 2 rows x PH, double
    const int H1 = 2 * PH;

    const int tid  = threadIdx.x;
    const int lane = tid & 63;
    const int wv   = tid >> 6;       // 0..7, each owns 16 units x 4 gates
    const int m    = lane & 15;
    const int kc   = lane >> 4;      // quad 0..3
    const int u0   = wv * 16;
    const int b0   = pair * 2;

    // zero h region (h0 = 0 for t=0)
    for (int i = tid; i < 4 * PH; i += 512) smh[i] = (_Float16)0.0f;

    // B-fragments: B[k=kc*8+j][n=col], col-major source
    h8 uf[4][4];                       // hot: every step
#pragma unroll
    for (int g = 0; g < 4; g++)
#pragma unroll
        for (int ks = 0; ks < 4; ks++)
            uf[g][ks] = *(const h8*)&Up[(g * 128 + u0 + m) * 128 + ks * 32 + kc * 8];
    h8 wf[4][KXS];                     // cold: once per 8 steps
#pragma unroll
    for (int g = 0; g < 4; g++)
#pragma unroll
        for (int ks = 0; ks < KXS; ks++)
            wf[g][ks] = *(const h8*)&Wp[(g * 128 + u0 + m) * KX + ks * 32 + kc * 8];
    float bias[4];
#pragma unroll
    for (int g = 0; g < 4; g++) bias[g] = bp[g * 128 + u0 + m];

    // consumer wait: hs block kblk is valid once prog[pair] > kblk.
    // Bounded spin (gives up after ~1s -> wrong output, never a hang).
    // NOTE: with a regular launch A never waits on B, so even with zero
    // co-residency this terminates (B runs after A completes).
    auto waitBlk = [&](int kblk) {
        if constexpr (!IS_A) {
            const int need = (kblk < 31 ? kblk : 31) + 1;
            int spins = 0;
            while (__hip_atomic_load(prog + pair, __ATOMIC_ACQUIRE,
                                     __HIP_MEMORY_SCOPE_AGENT) < need) {
                asm volatile("s_sleep 32");
                if (++spins > (1 << 20)) break;
            }
        }
    };

    // ---- x-block: packed-M x-projection, 8 steps/block ----
    // A row r16 = s*2 + brow; lane m supplies row m -> (step m>>1, brow m&1).
    f4 rX[4]; h8 rH[4];
    auto loadA = [&](int kblk) {
        int tt = kblk * 8 + (m >> 1); if (tt > T_STEPS - 1) tt = T_STEPS - 1;
        const int bb = b0 + (m & 1);
        if constexpr (IS_A) {
#pragma unroll
            for (int ks = 0; ks < KXS; ks++)
#pragma unroll
                for (int hf = 0; hf < 2; hf++)
                    rX[ks * 2 + hf] = *(const f4*)&xA[((size_t)bb * T_STEPS + tt) * FDIM
                                                      + ks * 32 + kc * 8 + hf * 4];
        } else {
#pragma unroll
            for (int ks = 0; ks < 4; ks++)
                rH[ks] = *(const h8*)&xB[((size_t)tt * BATCH + bb) * NU + ks * 32 + kc * 8];
        }
    };
    auto calcX = [&](int kblk) {       // regs -> xz half (kblk&1), f32
        float* xzw = &smxz[(kblk & 1) * 8192];
        f4 accx[4];
#pragma unroll
        for (int g = 0; g < 4; g++) accx[g] = (f4){bias[g], bias[g], bias[g], bias[g]};
#pragma unroll
        for (int ks = 0; ks < KXS; ks++) {
            h8 a;
            if constexpr (IS_A) {
#pragma unroll
                for (int j = 0; j < 4; j++) {
                    a[j]     = (_Float16)rX[ks * 2][j];
                    a[4 + j] = (_Float16)rX[ks * 2 + 1][j];
                }
            } else {
                a = rH[ks];
            }
#pragma unroll
            for (int g = 0; g < 4; g++)
                accx[g] = __builtin_amdgcn_mfma_f32_16x16x32_f16(a, wf[g][ks], accx[g], 0, 0, 0);
        }
        // C/D row r16 = kc*4+rr; write gate-vector f4 at [r16][u0+m]
#pragma unroll
        for (int rr = 0; rr < 4; rr++) {
            f4 v = {accx[0][rr], accx[1][rr], accx[2][rr], accx[3][rr]};
            *(f4*)&xzw[((kc * 4 + rr) * 128 + u0 + m) * 4] = v;
        }
    };

    waitBlk(0); loadA(0); calcX(0);    // block 0 -> half 0
    waitBlk(1); loadA(1);              // in flight for block 1
    __syncthreads();                   // xz half0 + zeroed H visible

    const h8 hzero = {};
    h8 ha[4];
#pragma unroll
    for (int ks = 0; ks < 4; ks++) ha[ks] = hzero;

    // loop-invariant zero C for MFMA chain starts (pinned: no per-step remat)
    f4 fzero = (f4){0.f, 0.f, 0.f, 0.f};
    asm volatile("" : "+v"(fzero));

    // epilogue identity: lanes 0..31 own (row=lane>>4, unit=u0+(lane&15))
    const int erow = lane >> 4;        // valid for lane<32
    float cst = 0.0f;

#pragma unroll 16
    for (int t = 0; t < T_STEPS; t++) {
        const int p = t & 1;
        const int s = t & 7;
        const int half = (t >> 3) & 1;

        if (s == 0) {
            int kn = (t >> 3) + 1;
            if (kn < T_STEPS / 8) {
                calcX(kn);             // consumes regs loaded 8 steps ago
                waitBlk(kn + 1);       // (B only) producer 2 blocks ahead?
                loadA(kn + 1);         // issue next block's loads (clamped)
            }
        }

        // xz gate-vector, issued early (consumed in epilogue)
        f4 xzv;
        if (lane < 32)
            xzv = *(const f4*)&smxz[half * 8192 + (s * 2 + erow) * 512 + (u0 + m) * 4];

        // A-frags for h@U: batch row 0 -> A-row 0 (m==0), row 1 -> A-row 4
        // (m==4) so C-row 4 lands in lanes 16..31 reg 0. Other rows garbage.
        if (m == 0 || m == 4) {
            const _Float16* hb = &smh[(p ? H1 : H0) + (m == 4 ? PH : 0)];
#pragma unroll
            for (int ks = 0; ks < 4; ks++)
                ha[ks] = *(const h8*)&hb[ks * 32 + kc * 8];
        }

        f4 acc[4];
#pragma unroll
        for (int g = 0; g < 4; g++)
            acc[g] = __builtin_amdgcn_mfma_f32_16x16x32_f16(ha[0], uf[g][0], fzero, 0, 0, 0);
#pragma unroll
        for (int ks = 1; ks < 4; ks++)
#pragma unroll
            for (int g = 0; g < 4; g++)
                acc[g] = __builtin_amdgcn_mfma_f32_16x16x32_f16(ha[ks], uf[g][ks], acc[g], 0, 0, 0);

        // epilogue on 32 lanes; z = acc[g][0] + xz (f32, exact)
        if (lane < 32) {
            float gi = sigm2(acc[0][0] + xzv[0]);
            float gf = sigm2(acc[1][0] + xzv[1]);
            float gg = tanh2(acc[2][0] + xzv[2]);
            float go = sigm2(acc[3][0] + xzv[3]);
            cst = gf * cst + gi * gg;
            float hv = go * tanh2(cst * TWOLOG2E);
            _Float16 h16 = (_Float16)hv;
            smh[(p ? H0 : H1) + erow * PH + u0 + m] = h16;
            if constexpr (IS_A)
                hs_out[((size_t)t * BATCH + b0 + erow) * NU + u0 + m] = h16;
        }

        if (IS_A && s == 7) {
            // publish completed 8-step block: drain this wave's global
            // stores, sync all waves, then one device-scope release-add.
            asm volatile("s_waitcnt vmcnt(0)" ::: "memory");
            __syncthreads();           // full drain + barrier (covers LDS dep)
            if (tid == 0) {
                __threadfence();
                __hip_atomic_fetch_add(prog + pair, 1, __ATOMIC_RELEASE,
                                       __HIP_MEMORY_SCOPE_AGENT);
            }
        } else {
            WG_BARRIER();              // LDS-only drain; vm stays in flight
        }
    }

    if constexpr (!IS_A) {
        // h(T): t=255 (p=1) wrote into H0
        if (wv == 0) {
            int rw = lane >> 5, u = lane & 31;
            float sacc = 0.0f;
#pragma unroll
            for (int j = 0; j < 4; j++) {
                int uum = u + j * 32;
                sacc += (float)smh[H0 + rw * PH + uum] * Wd[uum];
            }
            sacc += __shfl_xor(sacc, 16);
            sacc += __shfl_xor(sacc, 8);
            sacc += __shfl_xor(sacc, 4);
            sacc += __shfl_xor(sacc, 2);
            sacc += __shfl_xor(sacc, 1);
            if ((lane & 31) == 0) dout[b0 + rw] = fmaxf(sacc + bd[0], 0.0f);
        }
    }
}

// 512 WGs, regular launch: bid<256 -> layer A pair bid; bid>=256 -> layer B.
// 2 WGs/CU (67KB LDS, <=128 VGPR via launch_bounds min-waves=4); A and B WGs
// overlap on each CU when co-resident; plain serialization otherwise.
__global__ __launch_bounds__(512, 4) void lstm_dual(
    const float* __restrict__ x,
    const _Float16* __restrict__ Wp1, const _Float16* __restrict__ Up1,
    const float* __restrict__ bp1,
    const _Float16* __restrict__ Wp2, const _Float16* __restrict__ Up2,
    const float* __restrict__ bp2,
    _Float16* __restrict__ hs,
    const float* __restrict__ Wd, const float* __restrict__ bd,
    float* __restrict__ dout, int* __restrict__ prog) {
    __shared__ __align__(16) _Float16 smh[4 * PH];
    __shared__ __align__(16) float smxz[2 * 8192];
    const int bid = blockIdx.x;
    if (bid < 256)
        layer_body<true>(bid, x, nullptr, Wp1, Up1, bp1, hs,
                         nullptr, nullptr, nullptr, prog, smh, smxz);
    else
        layer_body<false>(bid - 256, nullptr, hs, Wp2, Up2, bp2, nullptr,
                          Wd, bd, dout, prog, smh, smxz);
}

extern "C" void kernel_launch(void* const* d_in, const int* in_sizes, int n_in,
                              void* d_out, int out_size, void* d_ws, size_t ws_size,
                              hipStream_t stream) {
    const float* x  = (const float*)d_in[0];
    const float* W1 = (const float*)d_in[1];
    const float* U1 = (const float*)d_in[2];
    const float* b1 = (const float*)d_in[3];
    const float* W2 = (const float*)d_in[4];
    const float* U2 = (const float*)d_in[5];
    const float* b2 = (const float*)d_in[6];
    const float* Wd = (const float*)d_in[7];
    const float* bd = (const float*)d_in[8];
    float* out = (float*)d_out;

    const size_t HS    = 33554432;             // hs fp16 [256][512][128]
    const size_t oWp1  = HS;
    const size_t oUp1  = oWp1 + 65536;
    const size_t oWp2  = oUp1 + 131072;
    const size_t oUp2  = oWp2 + 131072;
    const size_t oBp1  = oUp2 + 131072;
    const size_t oBp2  = oBp1 + 2048;
    const size_t oProg = oBp2 + 2048;
    const size_t need  = oProg + 2048;         // 34,019,328
    if (ws_size < need) return;

    char* ws = (char*)d_ws;
    _Float16* hs  = (_Float16*)ws;
    _Float16* Wp1 = (_Float16*)(ws + oWp1);
    _Float16* Up1 = (_Float16*)(ws + oUp1);
    _Float16* Wp2 = (_Float16*)(ws + oWp2);
    _Float16* Up2 = (_Float16*)(ws + oUp2);
    float*    bp1 = (float*)(ws + oBp1);
    float*    bp2 = (float*)(ws + oBp2);
    int*      prog = (int*)(ws + oProg);

    prep_weights<<<902, 256, 0, stream>>>(W1, U1, b1, W2, U2, b2,
                                          Wp1, Up1, Wp2, Up2, bp1, bp2, prog);
    lstm_dual<<<512, 512, 0, stream>>>(x, Wp1, Up1, bp1, Wp2, Up2, bp2,
                                       hs, Wd, bd, out, prog);
}

// Round 7
// 699.145 us; speedup vs baseline: 2.1044x; 2.1044x over previous
//
#include <hip/hip_runtime.h>

// SimpleLSTM: 2-layer LSTM (B=512,T=256,F=64,U=128) + Dense(1,relu).
// R15: VALIDATION ROUND - full-M layer structure (R14) run as two
// SEQUENTIAL kernels, no inter-WG handoff. R14 (dual + handoff) returned
// exactly-zero output; R13 proved the handoff protocol can work, so R14's
// failure is either the new full-M layer internals or cross-XCD staleness
// of the hs handoff under 64-WG dispatch. This round isolates the layer:
// kernel boundary replaces the progress counter. Structure per layer:
// WG = 16 batch rows (full MFMA M), 8 waves x (16 units x 4 gates);
// z = x@W + h@U via one chained asm-MFMA sequence per gate (B operand
// pinned in AGPRs, R11-proven macros); h ring = 8KB XOR-swizzled LDS dbuf
// (worst 2-way bank aliasing = free); bias added in epilogue (saves 12
// VGPRs vs C-splat). 32 WGs x 512 thr, 1 WG/CU, 2 waves/SIMD.
// If this passes, next round re-adds A/B overlap with system-scope fences.

#define T_STEPS 256
#define BATCH   512
#define NU      128
#define FDIM    64

typedef _Float16 h8 __attribute__((ext_vector_type(8)));
typedef float    f4 __attribute__((ext_vector_type(4)));

#define LOG2E    1.4426950408889634f
#define TWOLOG2E 2.8853900817779268f

// Workgroup barrier draining LDS only (global stores have no in-kernel
// reader -> drained at kernel end; global loads wait at use).
#define WG_BARRIER() asm volatile("s_waitcnt lgkmcnt(0)\n\ts_barrier" ::: "memory")

// Hot-loop MFMA: B operand from AGPR (builtins force v_accvgpr_read copies,
// R10). END variant embeds s_nop 7 so dependent VALU reads are >=8 wait
// states after the MFMA write (R11-proven on hardware).
#define MFMA16(d, a, b, c) \
    asm("v_mfma_f32_16x16x32_f16 %0, %1, %2, %3" : "=&v"(d) : "v"(a), "a"(b), "v"(c))
#define MFMA16_ACC(d, a, b) \
    asm("v_mfma_f32_16x16x32_f16 %0, %1, %2, %0" : "+v"(d) : "v"(a), "a"(b))
#define MFMA16_END(d, a, b) \
    asm("v_mfma_f32_16x16x32_f16 %0, %1, %2, %0\n\ts_nop 7" : "+v"(d) : "v"(a), "a"(b))

#if __has_builtin(__builtin_amdgcn_exp2f)
#define EXP2F(x) __builtin_amdgcn_exp2f(x)
#else
#define EXP2F(x) exp2f(x)
#endif
#if __has_builtin(__builtin_amdgcn_rcpf)
#define RCPF(x) __builtin_amdgcn_rcpf(x)
#else
#define RCPF(x) (1.0f / (x))
#endif

// s = -z*log2e (sign folded into weights) -> sigmoid(z)
__device__ __forceinline__ float sigm2(float s) {
    return RCPF(1.0f + EXP2F(s));
}
// t = 2*z*log2e -> tanh(z)
__device__ __forceinline__ float tanh2(float t) {
    return 1.0f - 2.0f * RCPF(1.0f + EXP2F(t));
}

// ---- weight prep: col-major [col][k], fp16, fold gate-specific log2e ----
// gates: 0=i 1=f 2=g 3=o ; i/f/o scaled by -log2e (sigm2), g by +2log2e.
__global__ void prep_weights(const float* __restrict__ W1, const float* __restrict__ U1,
                             const float* __restrict__ b1, const float* __restrict__ W2,
                             const float* __restrict__ U2, const float* __restrict__ b2,
                             _Float16* __restrict__ Wp1, _Float16* __restrict__ Up1,
                             _Float16* __restrict__ Wp2, _Float16* __restrict__ Up2,
                             float* __restrict__ bp1, float* __restrict__ bp2) {
    int i = blockIdx.x * 256 + threadIdx.x;
    if (i < 32768) {                       // Wp1 [512][64] from W1 [64][512]
        int col = i >> 6, k = i & 63;
        float sc = ((col >> 7) == 2) ? TWOLOG2E : -LOG2E;
        Wp1[i] = (_Float16)(W1[k * 512 + col] * sc);
    } else if (i < 32768 + 65536) {        // Up1 [512][128] from U1 [128][512]
        int j = i - 32768; int col = j >> 7, k = j & 127;
        float sc = ((col >> 7) == 2) ? TWOLOG2E : -LOG2E;
        Up1[j] = (_Float16)(U1[k * 512 + col] * sc);
    } else if (i < 32768 + 131072) {       // Wp2 [512][128] from W2 [128][512]
        int j = i - 98304; int col = j >> 7, k = j & 127;
        float sc = ((col >> 7) == 2) ? TWOLOG2E : -LOG2E;
        Wp2[j] = (_Float16)(W2[k * 512 + col] * sc);
    } else if (i < 32768 + 196608) {       // Up2 [512][128] from U2 [128][512]
        int j = i - 163840; int col = j >> 7, k = j & 127;
        float sc = ((col >> 7) == 2) ? TWOLOG2E : -LOG2E;
        Up2[j] = (_Float16)(U2[k * 512 + col] * sc);
    } else if (i < 32768 + 196608 + 1024) {
        int j = i - 229376;
        if (j < 512) {
            float sc = ((j >> 7) == 2) ? TWOLOG2E : -LOG2E;
            bp1[j] = b1[j] * sc;
        } else {
            int col = j - 512;
            float sc = ((col >> 7) == 2) ? TWOLOG2E : -LOG2E;
            bp2[col] = b2[col] * sc;
        }
    }
}

// LDS h layout: 2 bufs x 16 rows x 128 halfs (256B/row). The 16B-block
// column index is XOR-swizzled with (row&7): a wave's A-frag read (16 lanes
// = 16 rows at the same k-range) then spreads over all 32 banks (2 lanes/
// bank = free); unswizzled it would be a 16-way conflict.
__device__ __forceinline__ int hidx(int row, int k) {
    return row * 128 + ((((k >> 3) ^ (row & 7)) << 3) | (k & 7));
}

// ---- one LSTM layer, 16 batch rows/WG, full-M recurrence ----
// IS_A: input x f32 [B,T,F]; writes hs fp16 [T,B,U].
// !IS_A: input hs fp16 [T,B,U]; fused Dense(1,relu) tail.
template <bool IS_A>
__global__ __launch_bounds__(512)
__attribute__((amdgpu_waves_per_eu(2, 2))) void lstm16(
    const float* __restrict__ xA, const _Float16* __restrict__ hsIn,
    const _Float16* __restrict__ Wp,   // [512][KH*32] col-major, scaled fp16
    const _Float16* __restrict__ Up,   // [512][128] col-major, scaled fp16
    const float* __restrict__ bp,      // [512] scaled
    _Float16* __restrict__ hsOut,
    const float* __restrict__ Wd, const float* __restrict__ bd,
    float* __restrict__ dout) {
    constexpr int KH = IS_A ? 2 : 4;   // K-slices of the x/hs operand

    __shared__ __align__(16) _Float16 smh[4096];   // 8 KB: 2 bufs x 16 x 128

    const int tid  = threadIdx.x;
    const int lane = tid & 63;
    const int wv   = tid >> 6;         // 0..7: wave owns units u0..u0+15, 4 gates
    const int r15  = lane & 15;        // A-frag row / C col
    const int q    = lane >> 4;        // A-frag k-quad / C row-group
    const int u0   = wv * 16;
    const int row0 = blockIdx.x * 16;  // batch rows [row0, row0+16)

    for (int i = tid; i < 4096; i += 512) smh[i] = (_Float16)0.0f;

    // weights -> AGPRs (hot every step; asm MFMA consumes "a" directly)
    h8 uf[4][4], wf[4][KH];
#pragma unroll
    for (int g = 0; g < 4; g++) {
#pragma unroll
        for (int ks = 0; ks < 4; ks++) {
            uf[g][ks] = *(const h8*)&Up[(g * 128 + u0 + r15) * 128 + ks * 32 + q * 8];
            asm("" : "+a"(uf[g][ks]));
        }
#pragma unroll
        for (int ks = 0; ks < KH; ks++) {
            wf[g][ks] = *(const h8*)&Wp[(g * 128 + u0 + r15) * (KH * 32) + ks * 32 + q * 8];
            asm("" : "+a"(wf[g][ks]));
        }
    }
    // bias as 4 scalars, added in the epilogue (cheaper in VGPRs than C-splat)
    float bias[4];
#pragma unroll
    for (int g = 0; g < 4; g++) bias[g] = bp[g * 128 + u0 + r15];

    f4 cst = {0.0f, 0.0f, 0.0f, 0.0f};  // c-state rows q*4+0..3, unit u0+r15

    // loop-invariant zero C for MFMA chain starts (pinned: no per-step remat)
    f4 fzero = (f4){0.f, 0.f, 0.f, 0.f};
    asm volatile("" : "+v"(fzero));

    // input fragments
    h8 xa[2][KH];                       // B only: hs frag double-buffer
    f4 xraw[4];                         // A only: raw f32 x, 1-step prefetch

    auto loadFragB = [&](h8* dst, int t) {
        if constexpr (!IS_A) {
            const _Float16* p = &hsIn[((size_t)t * BATCH + row0 + r15) * NU + q * 8];
#pragma unroll
            for (int ks = 0; ks < 4; ks++)
                dst[ks] = *(const h8*)(p + ks * 32);
        }
    };
    auto loadXraw = [&](int t) {
        if constexpr (IS_A) {
            const float* p = &xA[((size_t)(row0 + r15) * T_STEPS + t) * FDIM + q * 8];
#pragma unroll
            for (int ks = 0; ks < 2; ks++) {
                xraw[ks * 2]     = *(const f4*)(p + ks * 32);
                xraw[ks * 2 + 1] = *(const f4*)(p + ks * 32 + 4);
            }
        }
    };

    if constexpr (IS_A) loadXraw(0);
    else                loadFragB(xa[0], 0);
    __syncthreads();                    // zeroed h visible

    for (int k = 0; k < 32; k++) {
#pragma unroll
        for (int s = 0; s < 8; s++) {
            const int t = k * 8 + s;
            const int tn = (t + 1 > 255) ? 255 : t + 1;

            // current input frag (A: convert f32->f16), prefetch next step
            h8 xc[2];
            if constexpr (IS_A) {
#pragma unroll
                for (int ks = 0; ks < 2; ks++) {
                    h8 a;
#pragma unroll
                    for (int j = 0; j < 4; j++) {
                        a[j]     = (_Float16)xraw[ks * 2][j];
                        a[4 + j] = (_Float16)xraw[ks * 2 + 1][j];
                    }
                    xc[ks] = a;
                }
                loadXraw(tn);
            } else {
                loadFragB(xa[(s & 1) ^ 1], tn);
            }

            // h(t-1) A-frag from LDS buf ((t&1)^1), swizzled read
            h8 ha[4];
            {
                const int rb = (((s & 1) ^ 1) << 11) + r15 * 128;
#pragma unroll
                for (int ks = 0; ks < 4; ks++)
                    ha[ks] = *(const h8*)&smh[rb + (((ks * 4 + q) ^ (r15 & 7)) << 3)];
            }

            // z = x@W + h@U, one chained asm-MFMA sequence per gate
            f4 az[4];
            if constexpr (IS_A) {
#pragma unroll
                for (int g = 0; g < 4; g++)
                    MFMA16(az[g], xc[0], wf[g][0], fzero);
#pragma unroll
                for (int g = 0; g < 4; g++)
                    MFMA16_ACC(az[g], xc[1], wf[g][1]);
            } else {
#pragma unroll
                for (int g = 0; g < 4; g++)
                    MFMA16(az[g], xa[s & 1][0], wf[g][0], fzero);
#pragma unroll
                for (int ks = 1; ks < 4; ks++)
#pragma unroll
                    for (int g = 0; g < 4; g++)
                        MFMA16_ACC(az[g], xa[s & 1][ks], wf[g][ks]);
            }
#pragma unroll
            for (int ks = 0; ks < 3; ks++)
#pragma unroll
                for (int g = 0; g < 4; g++)
                    MFMA16_ACC(az[g], ha[ks], uf[g][ks]);
#pragma unroll
            for (int g = 0; g < 4; g++)
                MFMA16_END(az[g], ha[3], uf[g][3]);

            // epilogue: 64 lanes x 4 rows (row = q*4+rr, unit u0+r15)
#pragma unroll
            for (int rr = 0; rr < 4; rr++) {
                float gi = sigm2(az[0][rr] + bias[0]);
                float gf = sigm2(az[1][rr] + bias[1]);
                float gg = tanh2(az[2][rr] + bias[2]);
                float go = sigm2(az[3][rr] + bias[3]);
                cst[rr] = gf * cst[rr] + gi * gg;
                float hv = go * tanh2(cst[rr] * TWOLOG2E);
                _Float16 h16 = (_Float16)hv;
                const int rowp = q * 4 + rr;
                smh[((s & 1) << 11) + hidx(rowp, u0 + r15)] = h16;
                if constexpr (IS_A)
                    hsOut[((size_t)t * BATCH + row0 + rowp) * NU + u0 + r15] = h16;
            }
            WG_BARRIER();
        }
    }

    if constexpr (!IS_A) {
        // Dense(1,relu): h(255) in buf 1 (t=255 -> s&1=1). Wave 0 only.
        if (wv == 0) {
            const int row = lane >> 2, kk = lane & 3;
            float sacc = 0.0f;
#pragma unroll
            for (int j = 0; j < 32; j++) {
                int kx = kk + 4 * j;
                sacc += (float)smh[2048 + hidx(row, kx)] * Wd[kx];
            }
            sacc += __shfl_xor(sacc, 2);
            sacc += __shfl_xor(sacc, 1);
            if (kk == 0) dout[row0 + row] = fmaxf(sacc + bd[0], 0.0f);
        }
    }
}

extern "C" void kernel_launch(void* const* d_in, const int* in_sizes, int n_in,
                              void* d_out, int out_size, void* d_ws, size_t ws_size,
                              hipStream_t stream) {
    const float* x  = (const float*)d_in[0];
    const float* W1 = (const float*)d_in[1];
    const float* U1 = (const float*)d_in[2];
    const float* b1 = (const float*)d_in[3];
    const float* W2 = (const float*)d_in[4];
    const float* U2 = (const float*)d_in[5];
    const float* b2 = (const float*)d_in[6];
    const float* Wd = (const float*)d_in[7];
    const float* bd = (const float*)d_in[8];
    float* out = (float*)d_out;

    const size_t HS   = 33554432;              // hs fp16 [256][512][128]
    const size_t oWp1 = HS;
    const size_t oUp1 = oWp1 + 65536;
    const size_t oWp2 = oUp1 + 131072;
    const size_t oUp2 = oWp2 + 131072;
    const size_t oBp1 = oUp2 + 131072;
    const size_t oBp2 = oBp1 + 2048;
    const size_t need = oBp2 + 2048;           // 34,017,280
    if (ws_size < need) return;

    char* ws = (char*)d_ws;
    _Float16* hs  = (_Float16*)ws;
    _Float16* Wp1 = (_Float16*)(ws + oWp1);
    _Float16* Up1 = (_Float16*)(ws + oUp1);
    _Float16* Wp2 = (_Float16*)(ws + oWp2);
    _Float16* Up2 = (_Float16*)(ws + oUp2);
    float*    bp1 = (float*)(ws + oBp1);
    float*    bp2 = (float*)(ws + oBp2);

    prep_weights<<<900, 256, 0, stream>>>(W1, U1, b1, W2, U2, b2,
                                          Wp1, Up1, Wp2, Up2, bp1, bp2);
    lstm16<true><<<32, 512, 0, stream>>>(x, nullptr, Wp1, Up1, bp1,
                                         hs, nullptr, nullptr, nullptr);
    lstm16<false><<<32, 512, 0, stream>>>(nullptr, hs, Wp2, Up2, bp2,
                                          nullptr, Wd, bd, out);
}